// Round 7
// baseline (353.945 us; speedup 1.0000x reference)
//
#include <hip/hip_runtime.h>
#include <math.h>

#define BB 8
#define SS 2048
#define DDIM 512
#define KC 1536
#define EPSV 1e-6f
#define SCALE 0.044194173824159216f   // 1/sqrt(512)

typedef unsigned short ushort_t;
using short8 = __attribute__((ext_vector_type(8))) short;
using f32x4  = __attribute__((ext_vector_type(4))) float;

__device__ inline unsigned short f2bf(float f) {
    union { float f; unsigned int u; } v; v.f = f;
    unsigned int r = v.u + 0x7FFFu + ((v.u >> 16) & 1u);   // RNE
    return (unsigned short)(r >> 16);
}
__device__ inline unsigned int packbf(float a, float b) {
    return (unsigned int)f2bf(a) | ((unsigned int)f2bf(b) << 16);
}
__device__ inline float bf2f(unsigned short s) {
    union { unsigned int u; float f; } v; v.u = ((unsigned int)s) << 16; return v.f;
}

// XOR-swizzled LDS tile (128 rows x 32 cols bf16 = 8KB, no pad).
// 16B unit of (row, colgroup g) = row*4 + (g ^ ((row>>2) & 3)).
// 16-lane phase analysis over the 8 16B-bank-groups:
//   staging store (rows 4k..4k+3, g=0..3): 16 consecutive units -> each group 2x (free).
//   fragment read (rows lm=0..15, g=lq fixed): rows 0-3 -> {g,g+4}x2, rows 4-7 -> {g^1,(g^1)+4}x2,
//   rows 8-11 -> {g^2,..}, rows 12-15 -> {g^3,..} -> all 8 groups exactly 2x (free).
// (R5's layout was 4-way on the store; R6's was 4-way on the read — both measured slow.)
__device__ inline void stfragS(ushort_t* s, int row, int g, uint4 v) {
    *reinterpret_cast<uint4*>(&s[(row * 4 + (g ^ ((row >> 2) & 3))) * 8]) = v;
}
__device__ inline short8 ldfragS(const ushort_t* s, int row, int lq) {
    return *reinterpret_cast<const short8*>(&s[(row * 4 + (lq ^ ((row >> 2) & 3))) * 8]);
}

// ---------- kx: x fp32 -> bf16 ----------
__global__ __launch_bounds__(256) void kx_cast(const float* __restrict__ x, ushort_t* __restrict__ xbf)
{
    int i = (blockIdx.x * 256 + threadIdx.x) * 4;
    float4 v = *reinterpret_cast<const float4*>(&x[i]);
    unsigned int lo = packbf(v.x, v.y), hi = packbf(v.z, v.w);
    *reinterpret_cast<uint2*>(&xbf[i]) = make_uint2(lo, hi);
}

// ---------- k0: weights -> bf16 (wcat for conv-as-GEMM, wqkv concat) ----------
__global__ __launch_bounds__(256) void k0_prep(
    const float* __restrict__ conv_w, const float* __restrict__ Wq,
    const float* __restrict__ Wk, const float* __restrict__ Wv,
    ushort_t* __restrict__ wcat, ushort_t* __restrict__ wqkv)
{
    int idx = blockIdx.x * 256 + threadIdx.x;   // < 512*1536
    {   // wcat[o][t*512+i] = conv_w[o][i][t]
        int o = idx / KC, kk = idx - o * KC;
        int t = kk >> 9, i = kk & 511;
        wcat[idx] = f2bf(conv_w[(size_t)o * KC + i * 3 + t]);
    }
    {   // wqkv[n][d], n<512: Wq ; n<1024: Wk ; else Wv
        int n = idx >> 9, d = idx & 511;
        const float* src = (n < 512) ? &Wq[(size_t)n * DDIM + d]
                         : (n < 1024) ? &Wk[(size_t)(n - 512) * DDIM + d]
                         : &Wv[(size_t)(n - 1024) * DDIM + d];
        wqkv[idx] = f2bf(*src);
    }
}

// ---------- k1b: conv as MFMA GEMM (K=1536 im2col via shifted rows) ----------
__global__ __launch_bounds__(256, 4) void k1b_conv(
    const ushort_t* __restrict__ xbf, const ushort_t* __restrict__ wcat,
    const float* __restrict__ conv_b, float* __restrict__ y, float* __restrict__ rs)
{
    __shared__ ushort_t As[4096];
    __shared__ ushort_t Bs[4096];
    const int t = threadIdx.x;
    const int lane = t & 63, w = t >> 6;
    const int lm = lane & 15, lq = lane >> 4;
    const int wm = w >> 1, wn = w & 1;
    const int srow = t >> 2, sg = t & 3, scol = (t & 3) * 8;
    const int s0 = blockIdx.x * 128;
    const int n0 = blockIdx.y * 128;
    const int b  = blockIdx.z;
    const ushort_t* Ag = xbf + (size_t)b * SS * DDIM;
    const ushort_t* Bg = wcat + (size_t)n0 * KC;

    f32x4 acc[4][4];
    #pragma unroll
    for (int i = 0; i < 4; i++)
        #pragma unroll
        for (int j = 0; j < 4; j++) acc[i][j] = (f32x4){0.f, 0.f, 0.f, 0.f};

    const uint4 z4 = make_uint4(0, 0, 0, 0);
    #define LOADA(dc, ro, dst) { \
        int s_ = s0 + srow + (ro) + ((dc) >> 4) - 1; \
        int ic_ = (((dc) & 15) << 5) + scol; \
        dst = (s_ >= 0 && s_ < SS) ? *reinterpret_cast<const uint4*>(&Ag[(size_t)s_ * DDIM + ic_]) : z4; }

    uint4 ra0, ra1, rb0, rb1;
    LOADA(0, 0, ra0); LOADA(0, 64, ra1);
    rb0 = *reinterpret_cast<const uint4*>(&Bg[(size_t)srow * KC + scol]);
    rb1 = *reinterpret_cast<const uint4*>(&Bg[(size_t)(srow + 64) * KC + scol]);

    for (int dc = 0; dc < 48; dc++) {
        stfragS(As, srow, sg, ra0);
        stfragS(As, srow + 64, sg, ra1);
        stfragS(Bs, srow, sg, rb0);
        stfragS(Bs, srow + 64, sg, rb1);
        __syncthreads();
        if (dc < 47) {
            LOADA(dc + 1, 0, ra0); LOADA(dc + 1, 64, ra1);
            int c = (dc + 1) * 32 + scol;
            rb0 = *reinterpret_cast<const uint4*>(&Bg[(size_t)srow * KC + c]);
            rb1 = *reinterpret_cast<const uint4*>(&Bg[(size_t)(srow + 64) * KC + c]);
        }
        short8 af[4];
        #pragma unroll
        for (int mt = 0; mt < 4; mt++)
            af[mt] = ldfragS(As, wm * 64 + mt * 16 + lm, lq);
        #pragma unroll
        for (int nt = 0; nt < 4; nt++) {
            short8 bfv = ldfragS(Bs, wn * 64 + nt * 16 + lm, lq);
            #pragma unroll
            for (int mt = 0; mt < 4; mt++)
                acc[mt][nt] = __builtin_amdgcn_mfma_f32_16x16x32_bf16(af[mt], bfv, acc[mt][nt], 0, 0, 0);
        }
        __syncthreads();
    }
    #undef LOADA

    // epilogue: +bias, write y fp32, row sumsq atomics
    const int rbase = s0 + wm * 64;
    const int cbase = n0 + wn * 64;
    float* yb  = y + (size_t)b * SS * DDIM;
    float* rsb = rs + (size_t)b * SS;
    float bias[4];
    #pragma unroll
    for (int nt = 0; nt < 4; nt++) bias[nt] = conv_b[cbase + nt * 16 + lm];
    #pragma unroll
    for (int mt = 0; mt < 4; mt++) {
        float pr[4] = {0.f, 0.f, 0.f, 0.f};
        #pragma unroll
        for (int nt = 0; nt < 4; nt++) {
            #pragma unroll
            for (int r = 0; r < 4; r++) {
                float val = acc[mt][nt][r] + bias[nt];
                yb[(size_t)(rbase + mt * 16 + lq * 4 + r) * DDIM + cbase + nt * 16 + lm] = val;
                pr[r] = fmaf(val, val, pr[r]);
            }
        }
        #pragma unroll
        for (int r = 0; r < 4; r++) {
            float p = pr[r];
            p += __shfl_xor(p, 1, 64); p += __shfl_xor(p, 2, 64);
            p += __shfl_xor(p, 4, 64); p += __shfl_xor(p, 8, 64);
            if (lm == 0) atomicAdd(&rsb[rbase + mt * 16 + lq * 4 + r], p);
        }
    }
}

// ---------- k1n: x_norm = y * rsqrt(rs/D+eps) * pre_g  -> bf16 ----------
__global__ __launch_bounds__(256) void k1n_norm(
    const float* __restrict__ y, const float* __restrict__ rs,
    const float* __restrict__ pre_g, ushort_t* __restrict__ xnbf)
{
    const int t = threadIdx.x;
    const int b = blockIdx.y;
    const int r0 = blockIdx.x * 8;
    float2 pg = *reinterpret_cast<const float2*>(&pre_g[2 * t]);
    for (int r = 0; r < 8; r++) {
        size_t row = (size_t)b * SS + r0 + r;
        float inv = rsqrtf(rs[row] * (1.0f / DDIM) + EPSV);
        float2 v = *reinterpret_cast<const float2*>(&y[row * DDIM + 2 * t]);
        *reinterpret_cast<unsigned int*>(&xnbf[row * DDIM + 2 * t]) =
            packbf(v.x * inv * pg.x, v.y * inv * pg.y);
    }
}

// ---------- k1c: QKV GEMM (N=1536 concat) ----------
__global__ __launch_bounds__(256, 4) void k1c_qkv(
    const ushort_t* __restrict__ xnbf, const ushort_t* __restrict__ wqkv,
    float* __restrict__ qraw, float* __restrict__ kraw, ushort_t* __restrict__ vb,
    float* __restrict__ rq, float* __restrict__ rk)
{
    __shared__ ushort_t As[4096];
    __shared__ ushort_t Bs[4096];
    const int t = threadIdx.x;
    const int lane = t & 63, w = t >> 6;
    const int lm = lane & 15, lq = lane >> 4;
    const int wm = w >> 1, wn = w & 1;
    const int srow = t >> 2, sg = t & 3, scol = (t & 3) * 8;
    const int s0 = blockIdx.x * 128;
    const int n0 = blockIdx.y * 128;
    const int b  = blockIdx.z;
    const ushort_t* Ag = xnbf + (size_t)b * SS * DDIM;
    const ushort_t* Bg = wqkv + (size_t)n0 * DDIM;

    f32x4 acc[4][4];
    #pragma unroll
    for (int i = 0; i < 4; i++)
        #pragma unroll
        for (int j = 0; j < 4; j++) acc[i][j] = (f32x4){0.f, 0.f, 0.f, 0.f};

    uint4 ra0 = *reinterpret_cast<const uint4*>(&Ag[(size_t)(s0 + srow) * DDIM + scol]);
    uint4 ra1 = *reinterpret_cast<const uint4*>(&Ag[(size_t)(s0 + srow + 64) * DDIM + scol]);
    uint4 rb0 = *reinterpret_cast<const uint4*>(&Bg[(size_t)srow * DDIM + scol]);
    uint4 rb1 = *reinterpret_cast<const uint4*>(&Bg[(size_t)(srow + 64) * DDIM + scol]);

    for (int dc = 0; dc < 16; dc++) {
        stfragS(As, srow, sg, ra0);
        stfragS(As, srow + 64, sg, ra1);
        stfragS(Bs, srow, sg, rb0);
        stfragS(Bs, srow + 64, sg, rb1);
        __syncthreads();
        if (dc < 15) {
            int c = (dc + 1) * 32 + scol;
            ra0 = *reinterpret_cast<const uint4*>(&Ag[(size_t)(s0 + srow) * DDIM + c]);
            ra1 = *reinterpret_cast<const uint4*>(&Ag[(size_t)(s0 + srow + 64) * DDIM + c]);
            rb0 = *reinterpret_cast<const uint4*>(&Bg[(size_t)srow * DDIM + c]);
            rb1 = *reinterpret_cast<const uint4*>(&Bg[(size_t)(srow + 64) * DDIM + c]);
        }
        short8 af[4];
        #pragma unroll
        for (int mt = 0; mt < 4; mt++)
            af[mt] = ldfragS(As, wm * 64 + mt * 16 + lm, lq);
        #pragma unroll
        for (int nt = 0; nt < 4; nt++) {
            short8 bfv = ldfragS(Bs, wn * 64 + nt * 16 + lm, lq);
            #pragma unroll
            for (int mt = 0; mt < 4; mt++)
                acc[mt][nt] = __builtin_amdgcn_mfma_f32_16x16x32_bf16(af[mt], bfv, acc[mt][nt], 0, 0, 0);
        }
        __syncthreads();
    }

    const int which = blockIdx.y >> 2;              // 0=q 1=k 2=v
    const int rbase = s0 + wm * 64;
    const int cbase = ((blockIdx.y & 3) * 128) + wn * 64;
    if (which == 2) {
        ushort_t* vbb = vb + (size_t)b * SS * DDIM;
        #pragma unroll
        for (int mt = 0; mt < 4; mt++)
            #pragma unroll
            for (int nt = 0; nt < 4; nt++)
                #pragma unroll
                for (int r = 0; r < 4; r++)
                    vbb[(size_t)(rbase + mt * 16 + lq * 4 + r) * DDIM + cbase + nt * 16 + lm] =
                        f2bf(acc[mt][nt][r]);
    } else {
        float* dst = which ? kraw : qraw;
        float* rr  = which ? rk : rq;
        float* db  = dst + (size_t)b * SS * DDIM;
        float* rb  = rr + (size_t)b * SS;
        #pragma unroll
        for (int mt = 0; mt < 4; mt++) {
            float pr[4] = {0.f, 0.f, 0.f, 0.f};
            #pragma unroll
            for (int nt = 0; nt < 4; nt++) {
                #pragma unroll
                for (int r = 0; r < 4; r++) {
                    float val = acc[mt][nt][r];
                    db[(size_t)(rbase + mt * 16 + lq * 4 + r) * DDIM + cbase + nt * 16 + lm] = val;
                    pr[r] = fmaf(val, val, pr[r]);
                }
            }
            #pragma unroll
            for (int r = 0; r < 4; r++) {
                float p = pr[r];
                p += __shfl_xor(p, 1, 64); p += __shfl_xor(p, 2, 64);
                p += __shfl_xor(p, 4, 64); p += __shfl_xor(p, 8, 64);
                if (lm == 0) atomicAdd(&rb[rbase + mt * 16 + lq * 4 + r], p);
            }
        }
    }
}

// ---------- k1d: rmsnorm(q,k) + rope -> bf16 ----------
__global__ __launch_bounds__(256) void k1d_rope(
    const float* __restrict__ qraw, const float* __restrict__ kraw,
    const float* __restrict__ rq, const float* __restrict__ rk,
    const float* __restrict__ q_g, const float* __restrict__ k_g,
    ushort_t* __restrict__ qb, ushort_t* __restrict__ kb)
{
    const int t = threadIdx.x;
    const int b = blockIdx.y;
    const int r0 = blockIdx.x * 8;
    const int c0 = 2 * t;
    float qg0 = q_g[c0], qg1 = q_g[c0 + 1];
    float kg0 = k_g[c0], kg1 = k_g[c0 + 1];
    float invf = (float)pow(10000.0, -(double)c0 / (double)DDIM);
    for (int r = 0; r < 8; r++) {
        int srow = r0 + r;
        size_t rowi = (size_t)b * SS + srow;
        float iq = rsqrtf(rq[rowi] * (1.0f / DDIM) + EPSV);
        float ik = rsqrtf(rk[rowi] * (1.0f / DDIM) + EPSV);
        size_t off = rowi * DDIM + c0;
        float2 qv = *reinterpret_cast<const float2*>(&qraw[off]);
        float2 kv = *reinterpret_cast<const float2*>(&kraw[off]);
        float q0 = qv.x * iq * qg0, q1 = qv.y * iq * qg1;
        float k0v = kv.x * ik * kg0, k1v = kv.y * ik * kg1;
        float ang = (float)srow * invf, sn, cs;
        sincosf(ang, &sn, &cs);
        *reinterpret_cast<unsigned int*>(&qb[off]) = packbf(q0 * cs - q1 * sn, q0 * sn + q1 * cs);
        *reinterpret_cast<unsigned int*>(&kb[off]) = packbf(k0v * cs - k1v * sn, k0v * sn + k1v * cs);
    }
}

// ---------- k2a: scores GEMM -> P (bf16, unnormalized exp) + row sums l ----------
__global__ __launch_bounds__(256, 4) void k2a_rowsum(
    const ushort_t* __restrict__ qb, const ushort_t* __restrict__ kb,
    ushort_t* __restrict__ P, float* __restrict__ l)
{
    __shared__ ushort_t As[4096];
    __shared__ ushort_t Bs[4096];
    const int t = threadIdx.x;
    const int lane = t & 63, w = t >> 6;
    const int lm = lane & 15, lq = lane >> 4;
    const int wm = w >> 1, wn = w & 1;
    const int srow = t >> 2, sg = t & 3, scol = (t & 3) * 8;

    const ushort_t* Ag = qb + ((size_t)blockIdx.z * SS + blockIdx.x * 128) * DDIM;
    const ushort_t* Bg = kb + ((size_t)blockIdx.z * SS + blockIdx.y * 128) * DDIM;

    f32x4 acc[4][4];
    #pragma unroll
    for (int i = 0; i < 4; i++)
        #pragma unroll
        for (int j = 0; j < 4; j++) acc[i][j] = (f32x4){0.f, 0.f, 0.f, 0.f};

    uint4 ra0 = *reinterpret_cast<const uint4*>(&Ag[(size_t)srow * DDIM + scol]);
    uint4 ra1 = *reinterpret_cast<const uint4*>(&Ag[(size_t)(srow + 64) * DDIM + scol]);
    uint4 rb0 = *reinterpret_cast<const uint4*>(&Bg[(size_t)srow * DDIM + scol]);
    uint4 rb1 = *reinterpret_cast<const uint4*>(&Bg[(size_t)(srow + 64) * DDIM + scol]);

    for (int dc = 0; dc < 16; dc++) {
        stfragS(As, srow, sg, ra0);
        stfragS(As, srow + 64, sg, ra1);
        stfragS(Bs, srow, sg, rb0);
        stfragS(Bs, srow + 64, sg, rb1);
        __syncthreads();
        if (dc < 15) {
            int off = (dc + 1) * 32 + scol;
            ra0 = *reinterpret_cast<const uint4*>(&Ag[(size_t)srow * DDIM + off]);
            ra1 = *reinterpret_cast<const uint4*>(&Ag[(size_t)(srow + 64) * DDIM + off]);
            rb0 = *reinterpret_cast<const uint4*>(&Bg[(size_t)srow * DDIM + off]);
            rb1 = *reinterpret_cast<const uint4*>(&Bg[(size_t)(srow + 64) * DDIM + off]);
        }
        short8 af[4];
        #pragma unroll
        for (int mt = 0; mt < 4; mt++)
            af[mt] = ldfragS(As, wm * 64 + mt * 16 + lm, lq);
        #pragma unroll
        for (int nt = 0; nt < 4; nt++) {
            short8 bfv = ldfragS(Bs, wn * 64 + nt * 16 + lm, lq);
            #pragma unroll
            for (int mt = 0; mt < 4; mt++)
                acc[mt][nt] = __builtin_amdgcn_mfma_f32_16x16x32_bf16(af[mt], bfv, acc[mt][nt], 0, 0, 0);
        }
        __syncthreads();
    }

    const int rbase = blockIdx.x * 128 + wm * 64;
    const int cbase = blockIdx.y * 128 + wn * 64;
    ushort_t* Pb = P + (size_t)blockIdx.z * SS * SS;
    float* lrow = l + (size_t)blockIdx.z * SS;
    #pragma unroll
    for (int mt = 0; mt < 4; mt++) {
        #pragma unroll
        for (int r = 0; r < 4; r++) {
            const int row = rbase + mt * 16 + lq * 4 + r;
            float rowp = 0.f;
            #pragma unroll
            for (int nt = 0; nt < 4; nt++) {
                float e = __expf(acc[mt][nt][r] * SCALE);
                Pb[(size_t)row * SS + cbase + nt * 16 + lm] = f2bf(e);
                rowp += e;
            }
            float p = rowp;
            p += __shfl_xor(p, 1, 64); p += __shfl_xor(p, 2, 64);
            p += __shfl_xor(p, 4, 64); p += __shfl_xor(p, 8, 64);
            if (lm == 0) atomicAdd(&lrow[row], p);
        }
    }
}

// ---------- k2c: cw[k] = sum_q P[q][k] / l[q] ----------
__global__ __launch_bounds__(256) void k2c_colred(
    const ushort_t* __restrict__ P, const float* __restrict__ l,
    float* __restrict__ cw)
{
    const int t = threadIdx.x;
    const int b = blockIdx.z;
    const int k0 = blockIdx.x * 512 + t * 2;
    const int q0 = blockIdx.y * 128;
    const ushort_t* Pb = P + ((size_t)b * SS + q0) * SS;
    const float* lb = l + (size_t)b * SS + q0;
    float a0 = 0.f, a1 = 0.f;
    for (int q = 0; q < 128; q++) {
        float rl = 1.0f / lb[q];
        unsigned int pp = *reinterpret_cast<const unsigned int*>(&Pb[(size_t)q * SS + k0]);
        a0 = fmaf(bf2f((ushort_t)(pp & 0xFFFF)), rl, a0);
        a1 = fmaf(bf2f((ushort_t)(pp >> 16)), rl, a1);
    }
    atomicAdd(&cw[(size_t)b * SS + k0], a0);
    atomicAdd(&cw[(size_t)b * SS + k0 + 1], a1);
}

// ---------- k4: out = (sum_s x + sum_k cw*v) / S ----------
__global__ __launch_bounds__(256) void k4_out(
    const float* __restrict__ x, const ushort_t* __restrict__ v,
    const float* __restrict__ cwv, float* __restrict__ out)
{
    const int b = blockIdx.x, c = blockIdx.y;
    const int t = threadIdx.x;
    const int srow0 = c * (SS / 16);
    const float* xb    = x + ((size_t)b * SS + srow0) * DDIM;
    const ushort_t* vb = v + ((size_t)b * SS + srow0) * DDIM;
    const float* cwb   = cwv + (size_t)b * SS + srow0;
    float a0 = 0.f, a1 = 0.f;
    for (int r = 0; r < SS / 16; r++) {
        float w = cwb[r];
        a0 += xb[(size_t)r * DDIM + t]       + w * bf2f(vb[(size_t)r * DDIM + t]);
        a1 += xb[(size_t)r * DDIM + t + 256] + w * bf2f(vb[(size_t)r * DDIM + t + 256]);
    }
    atomicAdd(&out[b * DDIM + t],       a0 * (1.0f / SS));
    atomicAdd(&out[b * DDIM + t + 256], a1 * (1.0f / SS));
}

extern "C" void kernel_launch(void* const* d_in, const int* in_sizes, int n_in,
                              void* d_out, int out_size, void* d_ws, size_t ws_size,
                              hipStream_t stream)
{
    const float* x      = (const float*)d_in[0];
    const float* conv_w = (const float*)d_in[1];
    const float* conv_b = (const float*)d_in[2];
    const float* pre_g  = (const float*)d_in[3];
    const float* q_g    = (const float*)d_in[4];
    const float* k_g    = (const float*)d_in[5];
    const float* Wq     = (const float*)d_in[6];
    const float* Wk     = (const float*)d_in[7];
    const float* Wv     = (const float*)d_in[8];
    float* out          = (float*)d_out;

    const size_t NTOK = (size_t)BB * SS * DDIM;   // 8.4M
    char* p = (char*)d_ws;
    float* y_qraw  = (float*)p; p += NTOK * 4;          // y, later qraw, later P (low half)
    float* kraw    = (float*)p; p += NTOK * 4;          // kraw, later P (high half)
    ushort_t* xbf_vb = (ushort_t*)p; p += NTOK * 2;     // xbf, later v
    ushort_t* xn_qb  = (ushort_t*)p; p += NTOK * 2;     // x_norm, later q(bf16)
    ushort_t* kb     = (ushort_t*)p; p += NTOK * 2;
    ushort_t* wcat   = (ushort_t*)p; p += (size_t)DDIM * KC * 2;
    ushort_t* wqkv   = (ushort_t*)p; p += (size_t)KC * DDIM * 2;
    float* rs   = (float*)p; p += (size_t)BB * SS * 4;
    float* rq   = (float*)p; p += (size_t)BB * SS * 4;
    float* rk   = (float*)p; p += (size_t)BB * SS * 4;
    float* lbuf = (float*)p; p += (size_t)BB * SS * 4;
    float* cwb  = (float*)p; p += (size_t)BB * SS * 4;

    // P (BB*SS*SS bf16 = 67 MB) aliases [y_qraw, kraw] (2 * 33.5 MB), dead after k1d.
    ushort_t* Pbuf = (ushort_t*)y_qraw;

    (void)hipMemsetAsync(d_out, 0, (size_t)out_size * sizeof(float), stream);
    (void)hipMemsetAsync(rs, 0, (size_t)BB * SS * 5 * sizeof(float), stream);

    kx_cast<<<dim3((unsigned)(NTOK / 1024)), 256, 0, stream>>>(x, xbf_vb);
    k0_prep<<<dim3(DDIM * KC / 256), 256, 0, stream>>>(conv_w, Wq, Wk, Wv, wcat, wqkv);
    k1b_conv<<<dim3(SS / 128, 4, BB), 256, 0, stream>>>(xbf_vb, wcat, conv_b, y_qraw, rs);
    k1n_norm<<<dim3(SS / 8, BB), 256, 0, stream>>>(y_qraw, rs, pre_g, xn_qb);
    k1c_qkv<<<dim3(SS / 128, 12, BB), 256, 0, stream>>>(xn_qb, wqkv, y_qraw, kraw, xbf_vb, rq, rk);
    k1d_rope<<<dim3(SS / 8, BB), 256, 0, stream>>>(y_qraw, kraw, rq, rk, q_g, k_g, xn_qb, kb);
    k2a_rowsum<<<dim3(SS / 128, SS / 128, BB), 256, 0, stream>>>(xn_qb, kb, Pbuf, lbuf);
    k2c_colred<<<dim3(SS / 512, SS / 128, BB), 256, 0, stream>>>(Pbuf, lbuf, cwb);
    k4_out<<<dim3(BB, 16), 256, 0, stream>>>(x, xbf_vb, cwb, out);
}

// Round 8
// 295.931 us; speedup vs baseline: 1.1960x; 1.1960x over previous
//
#include <hip/hip_runtime.h>
#include <math.h>

#define BB 8
#define SS 2048
#define DDIM 512
#define KC 1536
#define EPSV 1e-6f
#define SCALE 0.044194173824159216f   // 1/sqrt(512)
#define LDP 40   // padded LDS row (32 + 8 bf16). Empirically fastest (R4); read phase
                 // covers all 8 bank-groups 2x (5*lm mod 8), store ~2-way. Do not "improve".

typedef unsigned short ushort_t;
using short8 = __attribute__((ext_vector_type(8))) short;
using f32x4  = __attribute__((ext_vector_type(4))) float;

__device__ inline unsigned short f2bf(float f) {
    union { float f; unsigned int u; } v; v.f = f;
    unsigned int r = v.u + 0x7FFFu + ((v.u >> 16) & 1u);   // RNE
    return (unsigned short)(r >> 16);
}
__device__ inline unsigned int packbf(float a, float b) {
    return (unsigned int)f2bf(a) | ((unsigned int)f2bf(b) << 16);
}
__device__ inline float bf2f(unsigned short s) {
    union { unsigned int u; float f; } v; v.u = ((unsigned int)s) << 16; return v.f;
}
__device__ inline short8 ldfrag(const ushort_t* s, int row, int ko) {
    return *reinterpret_cast<const short8*>(&s[row * LDP + ko]);
}

// ---------- kx: x fp32 -> bf16 ----------
__global__ __launch_bounds__(256) void kx_cast(const float* __restrict__ x, ushort_t* __restrict__ xbf)
{
    int i = (blockIdx.x * 256 + threadIdx.x) * 4;
    float4 v = *reinterpret_cast<const float4*>(&x[i]);
    unsigned int lo = packbf(v.x, v.y), hi = packbf(v.z, v.w);
    *reinterpret_cast<uint2*>(&xbf[i]) = make_uint2(lo, hi);
}

// ---------- k0: weights -> bf16 (wcat for conv-as-GEMM, wqkv concat) ----------
__global__ __launch_bounds__(256) void k0_prep(
    const float* __restrict__ conv_w, const float* __restrict__ Wq,
    const float* __restrict__ Wk, const float* __restrict__ Wv,
    ushort_t* __restrict__ wcat, ushort_t* __restrict__ wqkv)
{
    int idx = blockIdx.x * 256 + threadIdx.x;   // < 512*1536
    {   // wcat[o][t*512+i] = conv_w[o][i][t]
        int o = idx / KC, kk = idx - o * KC;
        int t = kk >> 9, i = kk & 511;
        wcat[idx] = f2bf(conv_w[(size_t)o * KC + i * 3 + t]);
    }
    {   // wqkv[n][d], n<512: Wq ; n<1024: Wk ; else Wv
        int n = idx >> 9, d = idx & 511;
        const float* src = (n < 512) ? &Wq[(size_t)n * DDIM + d]
                         : (n < 1024) ? &Wk[(size_t)(n - 512) * DDIM + d]
                         : &Wv[(size_t)(n - 1024) * DDIM + d];
        wqkv[idx] = f2bf(*src);
    }
}

// ---------- k1b: conv as MFMA GEMM (K=1536 im2col via shifted rows) ----------
__global__ __launch_bounds__(256, 4) void k1b_conv(
    const ushort_t* __restrict__ xbf, const ushort_t* __restrict__ wcat,
    const float* __restrict__ conv_b, float* __restrict__ y, float* __restrict__ rs)
{
    __shared__ ushort_t As[128 * LDP];
    __shared__ ushort_t Bs[128 * LDP];
    const int t = threadIdx.x;
    const int lane = t & 63, w = t >> 6;
    const int lm = lane & 15, lq = lane >> 4;
    const int wm = w >> 1, wn = w & 1;
    const int srow = t >> 2, scol = (t & 3) * 8;
    const int s0 = blockIdx.x * 128;
    const int n0 = blockIdx.y * 128;
    const int b  = blockIdx.z;
    const ushort_t* Ag = xbf + (size_t)b * SS * DDIM;
    const ushort_t* Bg = wcat + (size_t)n0 * KC;

    f32x4 acc[4][4];
    #pragma unroll
    for (int i = 0; i < 4; i++)
        #pragma unroll
        for (int j = 0; j < 4; j++) acc[i][j] = (f32x4){0.f, 0.f, 0.f, 0.f};

    const uint4 z4 = make_uint4(0, 0, 0, 0);
    #define LOADA(dc, ro, dst) { \
        int s_ = s0 + srow + (ro) + ((dc) >> 4) - 1; \
        int ic_ = (((dc) & 15) << 5) + scol; \
        dst = (s_ >= 0 && s_ < SS) ? *reinterpret_cast<const uint4*>(&Ag[(size_t)s_ * DDIM + ic_]) : z4; }

    uint4 ra0, ra1, rb0, rb1;
    LOADA(0, 0, ra0); LOADA(0, 64, ra1);
    rb0 = *reinterpret_cast<const uint4*>(&Bg[(size_t)srow * KC + scol]);
    rb1 = *reinterpret_cast<const uint4*>(&Bg[(size_t)(srow + 64) * KC + scol]);

    for (int dc = 0; dc < 48; dc++) {
        *reinterpret_cast<uint4*>(&As[srow * LDP + scol]) = ra0;
        *reinterpret_cast<uint4*>(&As[(srow + 64) * LDP + scol]) = ra1;
        *reinterpret_cast<uint4*>(&Bs[srow * LDP + scol]) = rb0;
        *reinterpret_cast<uint4*>(&Bs[(srow + 64) * LDP + scol]) = rb1;
        __syncthreads();
        if (dc < 47) {
            LOADA(dc + 1, 0, ra0); LOADA(dc + 1, 64, ra1);
            int c = (dc + 1) * 32 + scol;
            rb0 = *reinterpret_cast<const uint4*>(&Bg[(size_t)srow * KC + c]);
            rb1 = *reinterpret_cast<const uint4*>(&Bg[(size_t)(srow + 64) * KC + c]);
        }
        short8 af[4];
        #pragma unroll
        for (int mt = 0; mt < 4; mt++)
            af[mt] = ldfrag(As, wm * 64 + mt * 16 + lm, lq * 8);
        #pragma unroll
        for (int nt = 0; nt < 4; nt++) {
            short8 bfv = ldfrag(Bs, wn * 64 + nt * 16 + lm, lq * 8);
            #pragma unroll
            for (int mt = 0; mt < 4; mt++)
                acc[mt][nt] = __builtin_amdgcn_mfma_f32_16x16x32_bf16(af[mt], bfv, acc[mt][nt], 0, 0, 0);
        }
        __syncthreads();
    }
    #undef LOADA

    // epilogue: +bias, write y fp32, row sumsq atomics
    const int rbase = s0 + wm * 64;
    const int cbase = n0 + wn * 64;
    float* yb  = y + (size_t)b * SS * DDIM;
    float* rsb = rs + (size_t)b * SS;
    float bias[4];
    #pragma unroll
    for (int nt = 0; nt < 4; nt++) bias[nt] = conv_b[cbase + nt * 16 + lm];
    #pragma unroll
    for (int mt = 0; mt < 4; mt++) {
        float pr[4] = {0.f, 0.f, 0.f, 0.f};
        #pragma unroll
        for (int nt = 0; nt < 4; nt++) {
            #pragma unroll
            for (int r = 0; r < 4; r++) {
                float val = acc[mt][nt][r] + bias[nt];
                yb[(size_t)(rbase + mt * 16 + lq * 4 + r) * DDIM + cbase + nt * 16 + lm] = val;
                pr[r] = fmaf(val, val, pr[r]);
            }
        }
        #pragma unroll
        for (int r = 0; r < 4; r++) {
            float p = pr[r];
            p += __shfl_xor(p, 1, 64); p += __shfl_xor(p, 2, 64);
            p += __shfl_xor(p, 4, 64); p += __shfl_xor(p, 8, 64);
            if (lm == 0) atomicAdd(&rsb[rbase + mt * 16 + lq * 4 + r], p);
        }
    }
}

// ---------- k1n: x_norm = y * rsqrt(rs/D+eps) * pre_g  -> bf16 ----------
__global__ __launch_bounds__(256) void k1n_norm(
    const float* __restrict__ y, const float* __restrict__ rs,
    const float* __restrict__ pre_g, ushort_t* __restrict__ xnbf)
{
    const int t = threadIdx.x;
    const int b = blockIdx.y;
    const int r0 = blockIdx.x * 8;
    float2 pg = *reinterpret_cast<const float2*>(&pre_g[2 * t]);
    for (int r = 0; r < 8; r++) {
        size_t row = (size_t)b * SS + r0 + r;
        float inv = rsqrtf(rs[row] * (1.0f / DDIM) + EPSV);
        float2 v = *reinterpret_cast<const float2*>(&y[row * DDIM + 2 * t]);
        *reinterpret_cast<unsigned int*>(&xnbf[row * DDIM + 2 * t]) =
            packbf(v.x * inv * pg.x, v.y * inv * pg.y);
    }
}

// ---------- k1c: QKV GEMM (N=1536 concat) ----------
__global__ __launch_bounds__(256, 4) void k1c_qkv(
    const ushort_t* __restrict__ xnbf, const ushort_t* __restrict__ wqkv,
    float* __restrict__ qraw, float* __restrict__ kraw, ushort_t* __restrict__ vb,
    float* __restrict__ rq, float* __restrict__ rk)
{
    __shared__ ushort_t As[128 * LDP];
    __shared__ ushort_t Bs[128 * LDP];
    const int t = threadIdx.x;
    const int lane = t & 63, w = t >> 6;
    const int lm = lane & 15, lq = lane >> 4;
    const int wm = w >> 1, wn = w & 1;
    const int srow = t >> 2, scol = (t & 3) * 8;
    const int s0 = blockIdx.x * 128;
    const int n0 = blockIdx.y * 128;
    const int b  = blockIdx.z;
    const ushort_t* Ag = xnbf + (size_t)b * SS * DDIM;
    const ushort_t* Bg = wqkv + (size_t)n0 * DDIM;

    f32x4 acc[4][4];
    #pragma unroll
    for (int i = 0; i < 4; i++)
        #pragma unroll
        for (int j = 0; j < 4; j++) acc[i][j] = (f32x4){0.f, 0.f, 0.f, 0.f};

    uint4 ra0 = *reinterpret_cast<const uint4*>(&Ag[(size_t)(s0 + srow) * DDIM + scol]);
    uint4 ra1 = *reinterpret_cast<const uint4*>(&Ag[(size_t)(s0 + srow + 64) * DDIM + scol]);
    uint4 rb0 = *reinterpret_cast<const uint4*>(&Bg[(size_t)srow * DDIM + scol]);
    uint4 rb1 = *reinterpret_cast<const uint4*>(&Bg[(size_t)(srow + 64) * DDIM + scol]);

    for (int dc = 0; dc < 16; dc++) {
        *reinterpret_cast<uint4*>(&As[srow * LDP + scol]) = ra0;
        *reinterpret_cast<uint4*>(&As[(srow + 64) * LDP + scol]) = ra1;
        *reinterpret_cast<uint4*>(&Bs[srow * LDP + scol]) = rb0;
        *reinterpret_cast<uint4*>(&Bs[(srow + 64) * LDP + scol]) = rb1;
        __syncthreads();
        if (dc < 15) {
            int c = (dc + 1) * 32 + scol;
            ra0 = *reinterpret_cast<const uint4*>(&Ag[(size_t)(s0 + srow) * DDIM + c]);
            ra1 = *reinterpret_cast<const uint4*>(&Ag[(size_t)(s0 + srow + 64) * DDIM + c]);
            rb0 = *reinterpret_cast<const uint4*>(&Bg[(size_t)srow * DDIM + c]);
            rb1 = *reinterpret_cast<const uint4*>(&Bg[(size_t)(srow + 64) * DDIM + c]);
        }
        short8 af[4];
        #pragma unroll
        for (int mt = 0; mt < 4; mt++)
            af[mt] = ldfrag(As, wm * 64 + mt * 16 + lm, lq * 8);
        #pragma unroll
        for (int nt = 0; nt < 4; nt++) {
            short8 bfv = ldfrag(Bs, wn * 64 + nt * 16 + lm, lq * 8);
            #pragma unroll
            for (int mt = 0; mt < 4; mt++)
                acc[mt][nt] = __builtin_amdgcn_mfma_f32_16x16x32_bf16(af[mt], bfv, acc[mt][nt], 0, 0, 0);
        }
        __syncthreads();
    }

    const int which = blockIdx.y >> 2;              // 0=q 1=k 2=v
    const int rbase = s0 + wm * 64;
    const int cbase = ((blockIdx.y & 3) * 128) + wn * 64;
    if (which == 2) {
        ushort_t* vbb = vb + (size_t)b * SS * DDIM;
        #pragma unroll
        for (int mt = 0; mt < 4; mt++)
            #pragma unroll
            for (int nt = 0; nt < 4; nt++)
                #pragma unroll
                for (int r = 0; r < 4; r++)
                    vbb[(size_t)(rbase + mt * 16 + lq * 4 + r) * DDIM + cbase + nt * 16 + lm] =
                        f2bf(acc[mt][nt][r]);
    } else {
        float* dst = which ? kraw : qraw;
        float* rr  = which ? rk : rq;
        float* db  = dst + (size_t)b * SS * DDIM;
        float* rb  = rr + (size_t)b * SS;
        #pragma unroll
        for (int mt = 0; mt < 4; mt++) {
            float pr[4] = {0.f, 0.f, 0.f, 0.f};
            #pragma unroll
            for (int nt = 0; nt < 4; nt++) {
                #pragma unroll
                for (int r = 0; r < 4; r++) {
                    float val = acc[mt][nt][r];
                    db[(size_t)(rbase + mt * 16 + lq * 4 + r) * DDIM + cbase + nt * 16 + lm] = val;
                    pr[r] = fmaf(val, val, pr[r]);
                }
            }
            #pragma unroll
            for (int r = 0; r < 4; r++) {
                float p = pr[r];
                p += __shfl_xor(p, 1, 64); p += __shfl_xor(p, 2, 64);
                p += __shfl_xor(p, 4, 64); p += __shfl_xor(p, 8, 64);
                if (lm == 0) atomicAdd(&rb[rbase + mt * 16 + lq * 4 + r], p);
            }
        }
    }
}

// ---------- k1d: rmsnorm(q,k) + rope -> bf16 ----------
__global__ __launch_bounds__(256) void k1d_rope(
    const float* __restrict__ qraw, const float* __restrict__ kraw,
    const float* __restrict__ rq, const float* __restrict__ rk,
    const float* __restrict__ q_g, const float* __restrict__ k_g,
    ushort_t* __restrict__ qb, ushort_t* __restrict__ kb)
{
    const int t = threadIdx.x;
    const int b = blockIdx.y;
    const int r0 = blockIdx.x * 8;
    const int c0 = 2 * t;
    float qg0 = q_g[c0], qg1 = q_g[c0 + 1];
    float kg0 = k_g[c0], kg1 = k_g[c0 + 1];
    float invf = (float)pow(10000.0, -(double)c0 / (double)DDIM);
    for (int r = 0; r < 8; r++) {
        int srow = r0 + r;
        size_t rowi = (size_t)b * SS + srow;
        float iq = rsqrtf(rq[rowi] * (1.0f / DDIM) + EPSV);
        float ik = rsqrtf(rk[rowi] * (1.0f / DDIM) + EPSV);
        size_t off = rowi * DDIM + c0;
        float2 qv = *reinterpret_cast<const float2*>(&qraw[off]);
        float2 kv = *reinterpret_cast<const float2*>(&kraw[off]);
        float q0 = qv.x * iq * qg0, q1 = qv.y * iq * qg1;
        float k0v = kv.x * ik * kg0, k1v = kv.y * ik * kg1;
        float ang = (float)srow * invf, sn, cs;
        sincosf(ang, &sn, &cs);
        *reinterpret_cast<unsigned int*>(&qb[off]) = packbf(q0 * cs - q1 * sn, q0 * sn + q1 * cs);
        *reinterpret_cast<unsigned int*>(&kb[off]) = packbf(k0v * cs - k1v * sn, k0v * sn + k1v * cs);
    }
}

// ---------- k2a: scores GEMM -> P (bf16, unnormalized exp) + row sums l ----------
__global__ __launch_bounds__(256, 4) void k2a_rowsum(
    const ushort_t* __restrict__ qb, const ushort_t* __restrict__ kb,
    ushort_t* __restrict__ P, float* __restrict__ l)
{
    __shared__ ushort_t As[128 * LDP];
    __shared__ ushort_t Bs[128 * LDP];
    const int t = threadIdx.x;
    const int lane = t & 63, w = t >> 6;
    const int lm = lane & 15, lq = lane >> 4;
    const int wm = w >> 1, wn = w & 1;
    const int srow = t >> 2, scol = (t & 3) * 8;

    const ushort_t* Ag = qb + ((size_t)blockIdx.z * SS + blockIdx.x * 128) * DDIM;
    const ushort_t* Bg = kb + ((size_t)blockIdx.z * SS + blockIdx.y * 128) * DDIM;

    f32x4 acc[4][4];
    #pragma unroll
    for (int i = 0; i < 4; i++)
        #pragma unroll
        for (int j = 0; j < 4; j++) acc[i][j] = (f32x4){0.f, 0.f, 0.f, 0.f};

    uint4 ra0 = *reinterpret_cast<const uint4*>(&Ag[(size_t)srow * DDIM + scol]);
    uint4 ra1 = *reinterpret_cast<const uint4*>(&Ag[(size_t)(srow + 64) * DDIM + scol]);
    uint4 rb0 = *reinterpret_cast<const uint4*>(&Bg[(size_t)srow * DDIM + scol]);
    uint4 rb1 = *reinterpret_cast<const uint4*>(&Bg[(size_t)(srow + 64) * DDIM + scol]);

    for (int dc = 0; dc < 16; dc++) {
        *reinterpret_cast<uint4*>(&As[srow * LDP + scol]) = ra0;
        *reinterpret_cast<uint4*>(&As[(srow + 64) * LDP + scol]) = ra1;
        *reinterpret_cast<uint4*>(&Bs[srow * LDP + scol]) = rb0;
        *reinterpret_cast<uint4*>(&Bs[(srow + 64) * LDP + scol]) = rb1;
        __syncthreads();
        if (dc < 15) {
            int off = (dc + 1) * 32 + scol;
            ra0 = *reinterpret_cast<const uint4*>(&Ag[(size_t)srow * DDIM + off]);
            ra1 = *reinterpret_cast<const uint4*>(&Ag[(size_t)(srow + 64) * DDIM + off]);
            rb0 = *reinterpret_cast<const uint4*>(&Bg[(size_t)srow * DDIM + off]);
            rb1 = *reinterpret_cast<const uint4*>(&Bg[(size_t)(srow + 64) * DDIM + off]);
        }
        short8 af[4];
        #pragma unroll
        for (int mt = 0; mt < 4; mt++)
            af[mt] = ldfrag(As, wm * 64 + mt * 16 + lm, lq * 8);
        #pragma unroll
        for (int nt = 0; nt < 4; nt++) {
            short8 bfv = ldfrag(Bs, wn * 64 + nt * 16 + lm, lq * 8);
            #pragma unroll
            for (int mt = 0; mt < 4; mt++)
                acc[mt][nt] = __builtin_amdgcn_mfma_f32_16x16x32_bf16(af[mt], bfv, acc[mt][nt], 0, 0, 0);
        }
        __syncthreads();
    }

    const int rbase = blockIdx.x * 128 + wm * 64;
    const int cbase = blockIdx.y * 128 + wn * 64;
    ushort_t* Pb = P + (size_t)blockIdx.z * SS * SS;
    float* lrow = l + (size_t)blockIdx.z * SS;
    #pragma unroll
    for (int mt = 0; mt < 4; mt++) {
        #pragma unroll
        for (int r = 0; r < 4; r++) {
            const int row = rbase + mt * 16 + lq * 4 + r;
            float rowp = 0.f;
            #pragma unroll
            for (int nt = 0; nt < 4; nt++) {
                float e = __expf(acc[mt][nt][r] * SCALE);
                Pb[(size_t)row * SS + cbase + nt * 16 + lm] = f2bf(e);
                rowp += e;
            }
            float p = rowp;
            p += __shfl_xor(p, 1, 64); p += __shfl_xor(p, 2, 64);
            p += __shfl_xor(p, 4, 64); p += __shfl_xor(p, 8, 64);
            if (lm == 0) atomicAdd(&lrow[row], p);
        }
    }
}

// ---------- k2c: cw[k] = sum_q P[q][k] / l[q] ----------
__global__ __launch_bounds__(256) void k2c_colred(
    const ushort_t* __restrict__ P, const float* __restrict__ l,
    float* __restrict__ cw)
{
    const int t = threadIdx.x;
    const int b = blockIdx.z;
    const int k0 = blockIdx.x * 512 + t * 2;
    const int q0 = blockIdx.y * 128;
    const ushort_t* Pb = P + ((size_t)b * SS + q0) * SS;
    const float* lb = l + (size_t)b * SS + q0;
    float a0 = 0.f, a1 = 0.f;
    for (int q = 0; q < 128; q++) {
        float rl = 1.0f / lb[q];
        unsigned int pp = *reinterpret_cast<const unsigned int*>(&Pb[(size_t)q * SS + k0]);
        a0 = fmaf(bf2f((ushort_t)(pp & 0xFFFF)), rl, a0);
        a1 = fmaf(bf2f((ushort_t)(pp >> 16)), rl, a1);
    }
    atomicAdd(&cw[(size_t)b * SS + k0], a0);
    atomicAdd(&cw[(size_t)b * SS + k0 + 1], a1);
}

// ---------- k4: out = (sum_s x + sum_k cw*v) / S ----------
__global__ __launch_bounds__(256) void k4_out(
    const float* __restrict__ x, const ushort_t* __restrict__ v,
    const float* __restrict__ cwv, float* __restrict__ out)
{
    const int b = blockIdx.x, c = blockIdx.y;
    const int t = threadIdx.x;
    const int srow0 = c * (SS / 16);
    const float* xb    = x + ((size_t)b * SS + srow0) * DDIM;
    const ushort_t* vb = v + ((size_t)b * SS + srow0) * DDIM;
    const float* cwb   = cwv + (size_t)b * SS + srow0;
    float a0 = 0.f, a1 = 0.f;
    for (int r = 0; r < SS / 16; r++) {
        float w = cwb[r];
        a0 += xb[(size_t)r * DDIM + t]       + w * bf2f(vb[(size_t)r * DDIM + t]);
        a1 += xb[(size_t)r * DDIM + t + 256] + w * bf2f(vb[(size_t)r * DDIM + t + 256]);
    }
    atomicAdd(&out[b * DDIM + t],       a0 * (1.0f / SS));
    atomicAdd(&out[b * DDIM + t + 256], a1 * (1.0f / SS));
}

extern "C" void kernel_launch(void* const* d_in, const int* in_sizes, int n_in,
                              void* d_out, int out_size, void* d_ws, size_t ws_size,
                              hipStream_t stream)
{
    const float* x      = (const float*)d_in[0];
    const float* conv_w = (const float*)d_in[1];
    const float* conv_b = (const float*)d_in[2];
    const float* pre_g  = (const float*)d_in[3];
    const float* q_g    = (const float*)d_in[4];
    const float* k_g    = (const float*)d_in[5];
    const float* Wq     = (const float*)d_in[6];
    const float* Wk     = (const float*)d_in[7];
    const float* Wv     = (const float*)d_in[8];
    float* out          = (float*)d_out;

    const size_t NTOK = (size_t)BB * SS * DDIM;   // 8.4M
    char* p = (char*)d_ws;
    float* y_qraw  = (float*)p; p += NTOK * 4;          // y, later qraw, later P (low half)
    float* kraw    = (float*)p; p += NTOK * 4;          // kraw, later P (high half)
    ushort_t* xbf_vb = (ushort_t*)p; p += NTOK * 2;     // xbf, later v
    ushort_t* xn_qb  = (ushort_t*)p; p += NTOK * 2;     // x_norm, later q(bf16)
    ushort_t* kb     = (ushort_t*)p; p += NTOK * 2;
    ushort_t* wcat   = (ushort_t*)p; p += (size_t)DDIM * KC * 2;
    ushort_t* wqkv   = (ushort_t*)p; p += (size_t)KC * DDIM * 2;
    float* rs   = (float*)p; p += (size_t)BB * SS * 4;
    float* rq   = (float*)p; p += (size_t)BB * SS * 4;
    float* rk   = (float*)p; p += (size_t)BB * SS * 4;
    float* lbuf = (float*)p; p += (size_t)BB * SS * 4;
    float* cwb  = (float*)p; p += (size_t)BB * SS * 4;

    // P (BB*SS*SS bf16 = 67 MB) aliases [y_qraw, kraw] (2 * 33.5 MB), dead after k1d.
    ushort_t* Pbuf = (ushort_t*)y_qraw;

    (void)hipMemsetAsync(d_out, 0, (size_t)out_size * sizeof(float), stream);
    (void)hipMemsetAsync(rs, 0, (size_t)BB * SS * 5 * sizeof(float), stream);

    kx_cast<<<dim3((unsigned)(NTOK / 1024)), 256, 0, stream>>>(x, xbf_vb);
    k0_prep<<<dim3(DDIM * KC / 256), 256, 0, stream>>>(conv_w, Wq, Wk, Wv, wcat, wqkv);
    k1b_conv<<<dim3(SS / 128, 4, BB), 256, 0, stream>>>(xbf_vb, wcat, conv_b, y_qraw, rs);
    k1n_norm<<<dim3(SS / 8, BB), 256, 0, stream>>>(y_qraw, rs, pre_g, xn_qb);
    k1c_qkv<<<dim3(SS / 128, 12, BB), 256, 0, stream>>>(xn_qb, wqkv, y_qraw, kraw, xbf_vb, rq, rk);
    k1d_rope<<<dim3(SS / 8, BB), 256, 0, stream>>>(y_qraw, kraw, rq, rk, q_g, k_g, xn_qb, kb);
    k2a_rowsum<<<dim3(SS / 128, SS / 128, BB), 256, 0, stream>>>(xn_qb, kb, Pbuf, lbuf);
    k2c_colred<<<dim3(SS / 512, SS / 128, BB), 256, 0, stream>>>(Pbuf, lbuf, cwb);
    k4_out<<<dim3(BB, 16), 256, 0, stream>>>(x, xbf_vb, cwb, out);
}

// Round 9
// 287.775 us; speedup vs baseline: 1.2299x; 1.0283x over previous
//
#include <hip/hip_runtime.h>
#include <math.h>

#define BB 8
#define SS 2048
#define DDIM 512
#define KC 1536
#define EPSV 1e-6f
#define SCALE 0.044194173824159216f   // 1/sqrt(512)
#define LDP 40   // padded LDS row (32 + 8 bf16). Empirically fastest (R4/R8); do not "improve".

typedef unsigned short ushort_t;
using short8 = __attribute__((ext_vector_type(8))) short;
using f32x4  = __attribute__((ext_vector_type(4))) float;

__device__ inline unsigned short f2bf(float f) {
    union { float f; unsigned int u; } v; v.f = f;
    unsigned int r = v.u + 0x7FFFu + ((v.u >> 16) & 1u);   // RNE
    return (unsigned short)(r >> 16);
}
__device__ inline unsigned int packbf(float a, float b) {
    return (unsigned int)f2bf(a) | ((unsigned int)f2bf(b) << 16);
}
__device__ inline float bf2f(unsigned short s) {
    union { unsigned int u; float f; } v; v.u = ((unsigned int)s) << 16; return v.f;
}
__device__ inline short8 ldfrag(const ushort_t* s, int row, int ko) {
    return *reinterpret_cast<const short8*>(&s[row * LDP + ko]);
}

// ---------- kx: x fp32 -> bf16 ----------
__global__ __launch_bounds__(256) void kx_cast(const float* __restrict__ x, ushort_t* __restrict__ xbf)
{
    int i = (blockIdx.x * 256 + threadIdx.x) * 4;
    float4 v = *reinterpret_cast<const float4*>(&x[i]);
    unsigned int lo = packbf(v.x, v.y), hi = packbf(v.z, v.w);
    *reinterpret_cast<uint2*>(&xbf[i]) = make_uint2(lo, hi);
}

// ---------- k0: weights -> bf16 ----------
__global__ __launch_bounds__(256) void k0_prep(
    const float* __restrict__ conv_w, const float* __restrict__ Wq,
    const float* __restrict__ Wk, const float* __restrict__ Wv,
    ushort_t* __restrict__ wcat, ushort_t* __restrict__ wqkv)
{
    int idx = blockIdx.x * 256 + threadIdx.x;   // < 512*1536
    {   // wcat[o][t*512+i] = conv_w[o][i][t]
        int o = idx / KC, kk = idx - o * KC;
        int t = kk >> 9, i = kk & 511;
        wcat[idx] = f2bf(conv_w[(size_t)o * KC + i * 3 + t]);
    }
    {   // wqkv[n][d]
        int n = idx >> 9, d = idx & 511;
        const float* src = (n < 512) ? &Wq[(size_t)n * DDIM + d]
                         : (n < 1024) ? &Wk[(size_t)(n - 512) * DDIM + d]
                         : &Wv[(size_t)(n - 1024) * DDIM + d];
        wqkv[idx] = f2bf(*src);
    }
}

// ---------- k1b: conv as MFMA GEMM (K=1536 im2col), y -> bf16 ----------
__global__ __launch_bounds__(256, 4) void k1b_conv(
    const ushort_t* __restrict__ xbf, const ushort_t* __restrict__ wcat,
    const float* __restrict__ conv_b, ushort_t* __restrict__ ybf, float* __restrict__ rs)
{
    __shared__ ushort_t As[128 * LDP];
    __shared__ ushort_t Bs[128 * LDP];
    const int t = threadIdx.x;
    const int lane = t & 63, w = t >> 6;
    const int lm = lane & 15, lq = lane >> 4;
    const int wm = w >> 1, wn = w & 1;
    const int srow = t >> 2, scol = (t & 3) * 8;
    const int s0 = blockIdx.x * 128;
    const int n0 = blockIdx.y * 128;
    const int b  = blockIdx.z;
    const ushort_t* Ag = xbf + (size_t)b * SS * DDIM;
    const ushort_t* Bg = wcat + (size_t)n0 * KC;

    f32x4 acc[4][4];
    #pragma unroll
    for (int i = 0; i < 4; i++)
        #pragma unroll
        for (int j = 0; j < 4; j++) acc[i][j] = (f32x4){0.f, 0.f, 0.f, 0.f};

    const uint4 z4 = make_uint4(0, 0, 0, 0);
    #define LOADA(dc, ro, dst) { \
        int s_ = s0 + srow + (ro) + ((dc) >> 4) - 1; \
        int ic_ = (((dc) & 15) << 5) + scol; \
        dst = (s_ >= 0 && s_ < SS) ? *reinterpret_cast<const uint4*>(&Ag[(size_t)s_ * DDIM + ic_]) : z4; }

    uint4 ra0, ra1, rb0, rb1;
    LOADA(0, 0, ra0); LOADA(0, 64, ra1);
    rb0 = *reinterpret_cast<const uint4*>(&Bg[(size_t)srow * KC + scol]);
    rb1 = *reinterpret_cast<const uint4*>(&Bg[(size_t)(srow + 64) * KC + scol]);

    for (int dc = 0; dc < 48; dc++) {
        *reinterpret_cast<uint4*>(&As[srow * LDP + scol]) = ra0;
        *reinterpret_cast<uint4*>(&As[(srow + 64) * LDP + scol]) = ra1;
        *reinterpret_cast<uint4*>(&Bs[srow * LDP + scol]) = rb0;
        *reinterpret_cast<uint4*>(&Bs[(srow + 64) * LDP + scol]) = rb1;
        __syncthreads();
        if (dc < 47) {
            LOADA(dc + 1, 0, ra0); LOADA(dc + 1, 64, ra1);
            int c = (dc + 1) * 32 + scol;
            rb0 = *reinterpret_cast<const uint4*>(&Bg[(size_t)srow * KC + c]);
            rb1 = *reinterpret_cast<const uint4*>(&Bg[(size_t)(srow + 64) * KC + c]);
        }
        short8 af[4];
        #pragma unroll
        for (int mt = 0; mt < 4; mt++)
            af[mt] = ldfrag(As, wm * 64 + mt * 16 + lm, lq * 8);
        #pragma unroll
        for (int nt = 0; nt < 4; nt++) {
            short8 bfv = ldfrag(Bs, wn * 64 + nt * 16 + lm, lq * 8);
            #pragma unroll
            for (int mt = 0; mt < 4; mt++)
                acc[mt][nt] = __builtin_amdgcn_mfma_f32_16x16x32_bf16(af[mt], bfv, acc[mt][nt], 0, 0, 0);
        }
        __syncthreads();
    }
    #undef LOADA

    // epilogue: +bias, write y bf16, row sumsq atomics (fp32 vals, pre-rounding)
    const int rbase = s0 + wm * 64;
    const int cbase = n0 + wn * 64;
    ushort_t* yb = ybf + (size_t)b * SS * DDIM;
    float* rsb = rs + (size_t)b * SS;
    float bias[4];
    #pragma unroll
    for (int nt = 0; nt < 4; nt++) bias[nt] = conv_b[cbase + nt * 16 + lm];
    #pragma unroll
    for (int mt = 0; mt < 4; mt++) {
        float pr[4] = {0.f, 0.f, 0.f, 0.f};
        #pragma unroll
        for (int nt = 0; nt < 4; nt++) {
            #pragma unroll
            for (int r = 0; r < 4; r++) {
                float val = acc[mt][nt][r] + bias[nt];
                yb[(size_t)(rbase + mt * 16 + lq * 4 + r) * DDIM + cbase + nt * 16 + lm] = f2bf(val);
                pr[r] = fmaf(val, val, pr[r]);
            }
        }
        #pragma unroll
        for (int r = 0; r < 4; r++) {
            float p = pr[r];
            p += __shfl_xor(p, 1, 64); p += __shfl_xor(p, 2, 64);
            p += __shfl_xor(p, 4, 64); p += __shfl_xor(p, 8, 64);
            if (lm == 0) atomicAdd(&rsb[rbase + mt * 16 + lq * 4 + r], p);
        }
    }
}

// ---------- k1n: x_norm = y * rsqrt(rs/D+eps) * pre_g  (bf16 in, bf16 out) ----------
__global__ __launch_bounds__(256) void k1n_norm(
    const ushort_t* __restrict__ ybf, const float* __restrict__ rs,
    const float* __restrict__ pre_g, ushort_t* __restrict__ xnbf)
{
    const int t = threadIdx.x;
    const int b = blockIdx.y;
    const int r0 = blockIdx.x * 8;
    float2 pg = *reinterpret_cast<const float2*>(&pre_g[2 * t]);
    for (int r = 0; r < 8; r++) {
        size_t row = (size_t)b * SS + r0 + r;
        float inv = rsqrtf(rs[row] * (1.0f / DDIM) + EPSV);
        unsigned int yv = *reinterpret_cast<const unsigned int*>(&ybf[row * DDIM + 2 * t]);
        float v0 = bf2f((ushort_t)(yv & 0xFFFF)), v1 = bf2f((ushort_t)(yv >> 16));
        *reinterpret_cast<unsigned int*>(&xnbf[row * DDIM + 2 * t]) =
            packbf(v0 * inv * pg.x, v1 * inv * pg.y);
    }
}

// ---------- k1c: QKV GEMM (N=1536 concat), q/k raw -> bf16 ----------
__global__ __launch_bounds__(256, 4) void k1c_qkv(
    const ushort_t* __restrict__ xnbf, const ushort_t* __restrict__ wqkv,
    ushort_t* __restrict__ qraw, ushort_t* __restrict__ kraw, ushort_t* __restrict__ vb,
    float* __restrict__ rq, float* __restrict__ rk)
{
    __shared__ ushort_t As[128 * LDP];
    __shared__ ushort_t Bs[128 * LDP];
    const int t = threadIdx.x;
    const int lane = t & 63, w = t >> 6;
    const int lm = lane & 15, lq = lane >> 4;
    const int wm = w >> 1, wn = w & 1;
    const int srow = t >> 2, scol = (t & 3) * 8;
    const int s0 = blockIdx.x * 128;
    const int n0 = blockIdx.y * 128;
    const int b  = blockIdx.z;
    const ushort_t* Ag = xnbf + (size_t)b * SS * DDIM;
    const ushort_t* Bg = wqkv + (size_t)n0 * DDIM;

    f32x4 acc[4][4];
    #pragma unroll
    for (int i = 0; i < 4; i++)
        #pragma unroll
        for (int j = 0; j < 4; j++) acc[i][j] = (f32x4){0.f, 0.f, 0.f, 0.f};

    uint4 ra0 = *reinterpret_cast<const uint4*>(&Ag[(size_t)(s0 + srow) * DDIM + scol]);
    uint4 ra1 = *reinterpret_cast<const uint4*>(&Ag[(size_t)(s0 + srow + 64) * DDIM + scol]);
    uint4 rb0 = *reinterpret_cast<const uint4*>(&Bg[(size_t)srow * DDIM + scol]);
    uint4 rb1 = *reinterpret_cast<const uint4*>(&Bg[(size_t)(srow + 64) * DDIM + scol]);

    for (int dc = 0; dc < 16; dc++) {
        *reinterpret_cast<uint4*>(&As[srow * LDP + scol]) = ra0;
        *reinterpret_cast<uint4*>(&As[(srow + 64) * LDP + scol]) = ra1;
        *reinterpret_cast<uint4*>(&Bs[srow * LDP + scol]) = rb0;
        *reinterpret_cast<uint4*>(&Bs[(srow + 64) * LDP + scol]) = rb1;
        __syncthreads();
        if (dc < 15) {
            int c = (dc + 1) * 32 + scol;
            ra0 = *reinterpret_cast<const uint4*>(&Ag[(size_t)(s0 + srow) * DDIM + c]);
            ra1 = *reinterpret_cast<const uint4*>(&Ag[(size_t)(s0 + srow + 64) * DDIM + c]);
            rb0 = *reinterpret_cast<const uint4*>(&Bg[(size_t)srow * DDIM + c]);
            rb1 = *reinterpret_cast<const uint4*>(&Bg[(size_t)(srow + 64) * DDIM + c]);
        }
        short8 af[4];
        #pragma unroll
        for (int mt = 0; mt < 4; mt++)
            af[mt] = ldfrag(As, wm * 64 + mt * 16 + lm, lq * 8);
        #pragma unroll
        for (int nt = 0; nt < 4; nt++) {
            short8 bfv = ldfrag(Bs, wn * 64 + nt * 16 + lm, lq * 8);
            #pragma unroll
            for (int mt = 0; mt < 4; mt++)
                acc[mt][nt] = __builtin_amdgcn_mfma_f32_16x16x32_bf16(af[mt], bfv, acc[mt][nt], 0, 0, 0);
        }
        __syncthreads();
    }

    const int which = blockIdx.y >> 2;              // 0=q 1=k 2=v
    const int rbase = s0 + wm * 64;
    const int cbase = ((blockIdx.y & 3) * 128) + wn * 64;
    if (which == 2) {
        ushort_t* vbb = vb + (size_t)b * SS * DDIM;
        #pragma unroll
        for (int mt = 0; mt < 4; mt++)
            #pragma unroll
            for (int nt = 0; nt < 4; nt++)
                #pragma unroll
                for (int r = 0; r < 4; r++)
                    vbb[(size_t)(rbase + mt * 16 + lq * 4 + r) * DDIM + cbase + nt * 16 + lm] =
                        f2bf(acc[mt][nt][r]);
    } else {
        ushort_t* db = (which ? kraw : qraw) + (size_t)b * SS * DDIM;
        float* rb = (which ? rk : rq) + (size_t)b * SS;
        #pragma unroll
        for (int mt = 0; mt < 4; mt++) {
            float pr[4] = {0.f, 0.f, 0.f, 0.f};
            #pragma unroll
            for (int nt = 0; nt < 4; nt++) {
                #pragma unroll
                for (int r = 0; r < 4; r++) {
                    float val = acc[mt][nt][r];
                    db[(size_t)(rbase + mt * 16 + lq * 4 + r) * DDIM + cbase + nt * 16 + lm] = f2bf(val);
                    pr[r] = fmaf(val, val, pr[r]);
                }
            }
            #pragma unroll
            for (int r = 0; r < 4; r++) {
                float p = pr[r];
                p += __shfl_xor(p, 1, 64); p += __shfl_xor(p, 2, 64);
                p += __shfl_xor(p, 4, 64); p += __shfl_xor(p, 8, 64);
                if (lm == 0) atomicAdd(&rb[rbase + mt * 16 + lq * 4 + r], p);
            }
        }
    }
}

// ---------- k1d: rmsnorm(q,k) + rope, IN-PLACE on bf16 buffers ----------
__global__ __launch_bounds__(256) void k1d_rope(
    ushort_t* q_io, ushort_t* k_io,
    const float* __restrict__ rq, const float* __restrict__ rk,
    const float* __restrict__ q_g, const float* __restrict__ k_g)
{
    const int t = threadIdx.x;
    const int b = blockIdx.y;
    const int r0 = blockIdx.x * 8;
    const int c0 = 2 * t;
    float qg0 = q_g[c0], qg1 = q_g[c0 + 1];
    float kg0 = k_g[c0], kg1 = k_g[c0 + 1];
    float invf = (float)pow(10000.0, -(double)c0 / (double)DDIM);
    for (int r = 0; r < 8; r++) {
        int srow = r0 + r;
        size_t rowi = (size_t)b * SS + srow;
        float iq = rsqrtf(rq[rowi] * (1.0f / DDIM) + EPSV);
        float ik = rsqrtf(rk[rowi] * (1.0f / DDIM) + EPSV);
        size_t off = rowi * DDIM + c0;
        unsigned int qv = *reinterpret_cast<const unsigned int*>(&q_io[off]);
        unsigned int kv = *reinterpret_cast<const unsigned int*>(&k_io[off]);
        float q0 = bf2f((ushort_t)(qv & 0xFFFF)) * iq * qg0;
        float q1 = bf2f((ushort_t)(qv >> 16)) * iq * qg1;
        float k0v = bf2f((ushort_t)(kv & 0xFFFF)) * ik * kg0;
        float k1v = bf2f((ushort_t)(kv >> 16)) * ik * kg1;
        float ang = (float)srow * invf, sn, cs;
        sincosf(ang, &sn, &cs);
        *reinterpret_cast<unsigned int*>(&q_io[off]) = packbf(q0 * cs - q1 * sn, q0 * sn + q1 * cs);
        *reinterpret_cast<unsigned int*>(&k_io[off]) = packbf(k0v * cs - k1v * sn, k0v * sn + k1v * cs);
    }
}

// ---------- k2a: scores GEMM -> P (bf16 unnormalized exp) + row sums l ----------
// Grid (BB, qtile, ktile): linear block id % 8 == batch -> all blocks of a batch
// land on one XCD (round-robin heuristic); per-batch Q+K (4 MB) fits its L2.
__global__ __launch_bounds__(256, 4) void k2a_rowsum(
    const ushort_t* __restrict__ qb, const ushort_t* __restrict__ kb,
    ushort_t* __restrict__ P, float* __restrict__ l)
{
    __shared__ ushort_t As[128 * LDP];
    __shared__ ushort_t Bs[128 * LDP];
    const int t = threadIdx.x;
    const int lane = t & 63, w = t >> 6;
    const int lm = lane & 15, lq = lane >> 4;
    const int wm = w >> 1, wn = w & 1;
    const int srow = t >> 2, scol = (t & 3) * 8;
    const int b  = blockIdx.x;
    const int qt = blockIdx.y;
    const int kt = blockIdx.z;

    const ushort_t* Ag = qb + ((size_t)b * SS + qt * 128) * DDIM;
    const ushort_t* Bg = kb + ((size_t)b * SS + kt * 128) * DDIM;

    f32x4 acc[4][4];
    #pragma unroll
    for (int i = 0; i < 4; i++)
        #pragma unroll
        for (int j = 0; j < 4; j++) acc[i][j] = (f32x4){0.f, 0.f, 0.f, 0.f};

    uint4 ra0 = *reinterpret_cast<const uint4*>(&Ag[(size_t)srow * DDIM + scol]);
    uint4 ra1 = *reinterpret_cast<const uint4*>(&Ag[(size_t)(srow + 64) * DDIM + scol]);
    uint4 rb0 = *reinterpret_cast<const uint4*>(&Bg[(size_t)srow * DDIM + scol]);
    uint4 rb1 = *reinterpret_cast<const uint4*>(&Bg[(size_t)(srow + 64) * DDIM + scol]);

    for (int dc = 0; dc < 16; dc++) {
        *reinterpret_cast<uint4*>(&As[srow * LDP + scol]) = ra0;
        *reinterpret_cast<uint4*>(&As[(srow + 64) * LDP + scol]) = ra1;
        *reinterpret_cast<uint4*>(&Bs[srow * LDP + scol]) = rb0;
        *reinterpret_cast<uint4*>(&Bs[(srow + 64) * LDP + scol]) = rb1;
        __syncthreads();
        if (dc < 15) {
            int off = (dc + 1) * 32 + scol;
            ra0 = *reinterpret_cast<const uint4*>(&Ag[(size_t)srow * DDIM + off]);
            ra1 = *reinterpret_cast<const uint4*>(&Ag[(size_t)(srow + 64) * DDIM + off]);
            rb0 = *reinterpret_cast<const uint4*>(&Bg[(size_t)srow * DDIM + off]);
            rb1 = *reinterpret_cast<const uint4*>(&Bg[(size_t)(srow + 64) * DDIM + off]);
        }
        short8 af[4];
        #pragma unroll
        for (int mt = 0; mt < 4; mt++)
            af[mt] = ldfrag(As, wm * 64 + mt * 16 + lm, lq * 8);
        #pragma unroll
        for (int nt = 0; nt < 4; nt++) {
            short8 bfv = ldfrag(Bs, wn * 64 + nt * 16 + lm, lq * 8);
            #pragma unroll
            for (int mt = 0; mt < 4; mt++)
                acc[mt][nt] = __builtin_amdgcn_mfma_f32_16x16x32_bf16(af[mt], bfv, acc[mt][nt], 0, 0, 0);
        }
        __syncthreads();
    }

    const int rbase = qt * 128 + wm * 64;
    const int cbase = kt * 128 + wn * 64;
    ushort_t* Pb = P + (size_t)b * SS * SS;
    float* lrow = l + (size_t)b * SS;
    #pragma unroll
    for (int mt = 0; mt < 4; mt++) {
        #pragma unroll
        for (int r = 0; r < 4; r++) {
            const int row = rbase + mt * 16 + lq * 4 + r;
            float rowp = 0.f;
            #pragma unroll
            for (int nt = 0; nt < 4; nt++) {
                float e = __expf(acc[mt][nt][r] * SCALE);
                Pb[(size_t)row * SS + cbase + nt * 16 + lm] = f2bf(e);
                rowp += e;
            }
            float p = rowp;
            p += __shfl_xor(p, 1, 64); p += __shfl_xor(p, 2, 64);
            p += __shfl_xor(p, 4, 64); p += __shfl_xor(p, 8, 64);
            if (lm == 0) atomicAdd(&lrow[row], p);
        }
    }
}

// ---------- k2c: cw[k] = sum_q P[q][k] / l[q] ----------
__global__ __launch_bounds__(256) void k2c_colred(
    const ushort_t* __restrict__ P, const float* __restrict__ l,
    float* __restrict__ cw)
{
    const int t = threadIdx.x;
    const int b = blockIdx.z;
    const int k0 = blockIdx.x * 1024 + t * 4;
    const int q0 = blockIdx.y * 128;
    const ushort_t* Pb = P + ((size_t)b * SS + q0) * SS;
    const float* lb = l + (size_t)b * SS + q0;
    float a0 = 0.f, a1 = 0.f, a2 = 0.f, a3 = 0.f;
    for (int q = 0; q < 128; q++) {
        float rl = 1.0f / lb[q];
        uint2 pp = *reinterpret_cast<const uint2*>(&Pb[(size_t)q * SS + k0]);
        a0 = fmaf(bf2f((ushort_t)(pp.x & 0xFFFF)), rl, a0);
        a1 = fmaf(bf2f((ushort_t)(pp.x >> 16)), rl, a1);
        a2 = fmaf(bf2f((ushort_t)(pp.y & 0xFFFF)), rl, a2);
        a3 = fmaf(bf2f((ushort_t)(pp.y >> 16)), rl, a3);
    }
    atomicAdd(&cw[(size_t)b * SS + k0], a0);
    atomicAdd(&cw[(size_t)b * SS + k0 + 1], a1);
    atomicAdd(&cw[(size_t)b * SS + k0 + 2], a2);
    atomicAdd(&cw[(size_t)b * SS + k0 + 3], a3);
}

// ---------- k4: out = (sum_s x + sum_k cw*v) / S ----------
__global__ __launch_bounds__(256) void k4_out(
    const float* __restrict__ x, const ushort_t* __restrict__ v,
    const float* __restrict__ cwv, float* __restrict__ out)
{
    const int b = blockIdx.x, c = blockIdx.y;
    const int t = threadIdx.x;
    const int srow0 = c * (SS / 16);
    const float* xb    = x + ((size_t)b * SS + srow0) * DDIM;
    const ushort_t* vb = v + ((size_t)b * SS + srow0) * DDIM;
    const float* cwb   = cwv + (size_t)b * SS + srow0;
    float a0 = 0.f, a1 = 0.f;
    for (int r = 0; r < SS / 16; r++) {
        float w = cwb[r];
        a0 += xb[(size_t)r * DDIM + t]       + w * bf2f(vb[(size_t)r * DDIM + t]);
        a1 += xb[(size_t)r * DDIM + t + 256] + w * bf2f(vb[(size_t)r * DDIM + t + 256]);
    }
    atomicAdd(&out[b * DDIM + t],       a0 * (1.0f / SS));
    atomicAdd(&out[b * DDIM + t + 256], a1 * (1.0f / SS));
}

extern "C" void kernel_launch(void* const* d_in, const int* in_sizes, int n_in,
                              void* d_out, int out_size, void* d_ws, size_t ws_size,
                              hipStream_t stream)
{
    const float* x      = (const float*)d_in[0];
    const float* conv_w = (const float*)d_in[1];
    const float* conv_b = (const float*)d_in[2];
    const float* pre_g  = (const float*)d_in[3];
    const float* q_g    = (const float*)d_in[4];
    const float* k_g    = (const float*)d_in[5];
    const float* Wq     = (const float*)d_in[6];
    const float* Wk     = (const float*)d_in[7];
    const float* Wv     = (const float*)d_in[8];
    float* out          = (float*)d_out;

    const size_t NTOK = (size_t)BB * SS * DDIM;   // 8.39M elements
    char* p = (char*)d_ws;
    // P region: 4 x NTOK bf16 = exactly BB*SS*SS*2 = 67.1 MB. All four sub-buffers
    // are dead by the time k2a writes P (xbf after k1b, ybf after k1n, xn after k1c).
    ushort_t* xbf = (ushort_t*)p; p += NTOK * 2;
    ushort_t* ybf = (ushort_t*)p; p += NTOK * 2;
    ushort_t* xn  = (ushort_t*)p; p += NTOK * 2;
    /* pad */                     p += NTOK * 2;
    ushort_t* qio = (ushort_t*)p; p += NTOK * 2;   // qraw, then q (in-place rope)
    ushort_t* kio = (ushort_t*)p; p += NTOK * 2;   // kraw, then k
    ushort_t* vb  = (ushort_t*)p; p += NTOK * 2;
    ushort_t* wcat = (ushort_t*)p; p += (size_t)DDIM * KC * 2;
    ushort_t* wqkv = (ushort_t*)p; p += (size_t)KC * DDIM * 2;
    float* rs   = (float*)p; p += (size_t)BB * SS * 4;
    float* rq   = (float*)p; p += (size_t)BB * SS * 4;
    float* rk   = (float*)p; p += (size_t)BB * SS * 4;
    float* lbuf = (float*)p; p += (size_t)BB * SS * 4;
    float* cwb  = (float*)p; p += (size_t)BB * SS * 4;

    ushort_t* Pbuf = xbf;   // 67.1 MB aliased region

    (void)hipMemsetAsync(d_out, 0, (size_t)out_size * sizeof(float), stream);
    (void)hipMemsetAsync(rs, 0, (size_t)BB * SS * 5 * sizeof(float), stream);

    kx_cast<<<dim3((unsigned)(NTOK / 1024)), 256, 0, stream>>>(x, xbf);
    k0_prep<<<dim3(DDIM * KC / 256), 256, 0, stream>>>(conv_w, Wq, Wk, Wv, wcat, wqkv);
    k1b_conv<<<dim3(SS / 128, 4, BB), 256, 0, stream>>>(xbf, wcat, conv_b, ybf, rs);
    k1n_norm<<<dim3(SS / 8, BB), 256, 0, stream>>>(ybf, rs, pre_g, xn);
    k1c_qkv<<<dim3(SS / 128, 12, BB), 256, 0, stream>>>(xn, wqkv, qio, kio, vb, rq, rk);
    k1d_rope<<<dim3(SS / 8, BB), 256, 0, stream>>>(qio, kio, rq, rk, q_g, k_g);
    k2a_rowsum<<<dim3(BB, SS / 128, SS / 128), 256, 0, stream>>>(qio, kio, Pbuf, lbuf);
    k2c_colred<<<dim3(SS / 1024, SS / 128, BB), 256, 0, stream>>>(Pbuf, lbuf, cwb);
    k4_out<<<dim3(BB, 16), 256, 0, stream>>>(x, vb, cwb, out);
}